// Round 5
// baseline (1305.398 us; speedup 1.0000x reference)
//
#include <hip/hip_runtime.h>
#include <hip/hip_bf16.h>

#define HDIM 512
#define TILE 32
#define TPB 256

typedef __attribute__((ext_vector_type(8))) short short8;
typedef __attribute__((ext_vector_type(4))) float f32x4;

__device__ __forceinline__ unsigned short f2bf(float x) {
  __hip_bfloat16 h = __float2bfloat16(x);
  return *reinterpret_cast<unsigned short*>(&h);
}
__device__ __forceinline__ float bf2f(unsigned short h) {
  return __uint_as_float(((unsigned)h) << 16);
}
// sigmoid via v_rcp_f32 (1-ulp) instead of IEEE divide (~10 ops).
__device__ __forceinline__ float fsig(float z) {
  return __builtin_amdgcn_rcpf(1.f + __expf(-z));
}
// XOR-swizzled ushort index into [row][col] bf16 tile, row stride 512 elems.
__device__ __forceinline__ int swz(int row, int col) {
  int xb = ((row & 12) >> 1) | (row & 1);
  return (((row << 10) + (col << 1)) ^ (xb << 4)) >> 1;
}

// W2 (512x512 f32 [k][n]) -> bf16 MFMA-fragment-major, fwd B[k][n] and bwd B[n][k].
__global__ void prep_weights(const float* __restrict__ pW2, const float* __restrict__ tW2,
                             unsigned short* __restrict__ pWf, unsigned short* __restrict__ pWb,
                             unsigned short* __restrict__ tWf, unsigned short* __restrict__ tWb) {
  int i = blockIdx.x * blockDim.x + threadIdx.x;
  if (i >= HDIM * HDIM) return;
  int j  = i & 7;
  int l  = (i >> 3) & 63;
  int kb = (i >> 9) & 15;
  int nb = i >> 13;
  int kpos = kb * 32 + ((l >> 4) << 3) + j;
  int npos = nb * 16 + (l & 15);
  pWf[i] = f2bf(pW2[kpos * HDIM + npos]);
  pWb[i] = f2bf(pW2[npos * HDIM + kpos]);
  tWf[i] = f2bf(tW2[kpos * HDIM + npos]);
  tWb[i] = f2bf(tW2[npos * HDIM + kpos]);
}

// W1 ([IN][512] f32) -> layer-1 MFMA B-fragments (hi/lo split-bf16, K=32 zero
// padded) and phase-5 B-fragments (dh0 GEMM: B[k][n]=W1[n][k], n<GD).
__global__ void prep_w1(const float* __restrict__ W1, int IN, int GD,
                        unsigned short* __restrict__ hi, unsigned short* __restrict__ lo,
                        unsigned short* __restrict__ p5) {
  int i = blockIdx.x * blockDim.x + threadIdx.x;
  if (i < 32 * 64 * 8) {               // layer-1 frags: [nb=32][lane][j]
    int j = i & 7, l = (i >> 3) & 63, nb = i >> 9;
    int k = ((l >> 4) << 3) + j;
    int col = nb * 16 + (l & 15);
    float v = (k < IN) ? W1[k * HDIM + col] : 0.f;
    unsigned short h = f2bf(v);
    hi[i] = h;
    lo[i] = f2bf(v - bf2f(h));
  } else if (i < 32 * 64 * 8 + 16 * 64 * 8) {  // phase-5 frags: [kk=16][lane][j]
    int i2 = i - 32 * 64 * 8;
    int j = i2 & 7, l = (i2 >> 3) & 63, kk = i2 >> 9;
    int lm = l & 15, q = l >> 4;
    int k = kk * 32 + q * 8 + j;
    p5[i2] = f2bf((lm < GD) ? W1[lm * HDIM + k] : 0.f);
  }
}

template <int ARITY>
__global__ void __launch_bounds__(TPB, 4)
energy_kernel(const float* __restrict__ x, const float* __restrict__ sigp,
              const int* __restrict__ edges, int Etot,
              const unsigned short* __restrict__ W1hi, const unsigned short* __restrict__ W1lo,
              const unsigned short* __restrict__ W1p5, const float* __restrict__ b1,
              const unsigned short* __restrict__ Wf, const unsigned short* __restrict__ Wb,
              const float* __restrict__ b2, const float* __restrict__ w3,
              const float* __restrict__ b3p, float* __restrict__ out) {
  constexpr int GD = 2 * ARITY;   // grad components per edge
  __shared__ __align__(16) unsigned short bufA[TILE * HDIM];  // h1 -> dz2 -> dz1 (32 KB)
  __shared__ __align__(16) float h0s[TILE][16];
  __shared__ float dh0s[TILE][8];
  __shared__ int   idxs[TILE * ARITY];
  __shared__ float blockE;

  const int tid  = threadIdx.x;
  const int lane = tid & 63;
  const int w    = tid >> 6;            // 4 waves
  const int q    = lane >> 4;
  const int lm   = lane & 15;
  const int tile0 = blockIdx.x * TILE;
  const int vcnt  = min(TILE, Etot - tile0);
  const float sigma = sigp[0];

  // ---- phase 0: init ----
  if (tid == 0) blockE = 0.f;
  ((float*)dh0s)[tid] = 0.f;            // 32*8 == 256 == TPB
  if (tid < TILE * ARITY) {
    int e = tid / ARITY;
    idxs[tid] = (e < vcnt) ? edges[(size_t)tile0 * ARITY + tid] : 0;
  }
  __syncthreads();
  if (tid < TILE) {
#pragma unroll
    for (int k = 0; k < 16; ++k) h0s[tid][k] = 0.f;
    if (tid < vcnt) {
#pragma unroll
      for (int o = 0; o < ARITY; ++o) {
        int id = idxs[tid * ARITY + o];
        h0s[tid][o * 2 + 0] = x[id * 2 + 0];
        h0s[tid][o * 2 + 1] = x[id * 2 + 1];
        h0s[tid][ARITY * 2 + o] = sigma;
      }
    }
  }
  __syncthreads();

  const int n0 = w * 128;               // wave owns 128 output cols

  // ---- phase 1: layer 1 via split-bf16 MFMA ----
  short8 Ah[2], Al[2];
#pragma unroll
  for (int mf = 0; mf < 2; ++mf) {
    f32x4 v0 = {0.f, 0.f, 0.f, 0.f}, v1 = {0.f, 0.f, 0.f, 0.f};
    if (q < 2) {
      const float* p = &h0s[mf * 16 + lm][q * 8];
      v0 = *(const f32x4*)p;
      v1 = *(const f32x4*)(p + 4);
    }
#pragma unroll
    for (int j = 0; j < 4; ++j) {
      unsigned short ha = f2bf(v0[j]);
      Ah[mf][j] = (short)ha;
      Al[mf][j] = (short)f2bf(v0[j] - bf2f(ha));
      unsigned short hb = f2bf(v1[j]);
      Ah[mf][j + 4] = (short)hb;
      Al[mf][j + 4] = (short)f2bf(v1[j] - bf2f(hb));
    }
  }

  f32x4 acc[2][8];
#pragma unroll
  for (int mf = 0; mf < 2; ++mf)
#pragma unroll
    for (int nf = 0; nf < 8; ++nf) acc[mf][nf] = (f32x4){0.f, 0.f, 0.f, 0.f};

#pragma unroll
  for (int nf = 0; nf < 8; ++nf) {
    short8 Bh = *(const short8*)(W1hi + (((w * 8 + nf) * 64 + lane) << 3));
    short8 Bl = *(const short8*)(W1lo + (((w * 8 + nf) * 64 + lane) << 3));
#pragma unroll
    for (int mf = 0; mf < 2; ++mf) {
      acc[mf][nf] = __builtin_amdgcn_mfma_f32_16x16x32_bf16(Ah[mf], Bh, acc[mf][nf], 0, 0, 0);
      acc[mf][nf] = __builtin_amdgcn_mfma_f32_16x16x32_bf16(Al[mf], Bh, acc[mf][nf], 0, 0, 0);
      acc[mf][nf] = __builtin_amdgcn_mfma_f32_16x16x32_bf16(Ah[mf], Bl, acc[mf][nf], 0, 0, 0);
    }
  }

  // silu(z1) -> bufA (bf16)
#pragma unroll
  for (int nf = 0; nf < 8; ++nf) {
    float b1n = b1[n0 + nf * 16 + lm];
#pragma unroll
    for (int mf = 0; mf < 2; ++mf)
#pragma unroll
      for (int r = 0; r < 4; ++r) {
        int row = mf * 16 + q * 4 + r;
        float z = acc[mf][nf][r] + b1n;
        float s = fsig(z);
        float hv = (row < vcnt) ? z * s : 0.f;
        bufA[swz(row, n0 + nf * 16 + lm)] = f2bf(hv);
      }
  }
  __syncthreads();

  // ---- phase 2: forward GEMM z2 = h1 @ W2 ----
#pragma unroll
  for (int mf = 0; mf < 2; ++mf)
#pragma unroll
    for (int nf = 0; nf < 8; ++nf) acc[mf][nf] = (f32x4){0.f, 0.f, 0.f, 0.f};

#pragma unroll 4
  for (int kk = 0; kk < 16; ++kk) {
    short8 a[2];
#pragma unroll
    for (int mf = 0; mf < 2; ++mf)
      a[mf] = *(const short8*)&bufA[swz(mf * 16 + lm, kk * 32 + q * 8)];
#pragma unroll
    for (int nf = 0; nf < 8; ++nf) {
      short8 bfr = *(const short8*)(Wf + ((((w * 8 + nf) * 16 + kk) * 64 + lane) << 3));
#pragma unroll
      for (int mf = 0; mf < 2; ++mf)
        acc[mf][nf] = __builtin_amdgcn_mfma_f32_16x16x32_bf16(a[mf], bfr, acc[mf][nf], 0, 0, 0);
    }
  }

  // ---- epilogue fwd: energy + dz2 = w3*silu'(z2) ----
  float epart = 0.f;
#pragma unroll
  for (int nf = 0; nf < 8; ++nf) {
    float b2n = b2[n0 + nf * 16 + lm];
    float w3n = w3[n0 + nf * 16 + lm];
#pragma unroll
    for (int mf = 0; mf < 2; ++mf)
#pragma unroll
      for (int r = 0; r < 4; ++r) {
        int row = mf * 16 + q * 4 + r;
        bool val = row < vcnt;
        float z = acc[mf][nf][r] + b2n;
        float s = fsig(z);
        float h2 = z * s;
        float sp = s * (1.f + z * (1.f - s));
        epart += val ? h2 * w3n : 0.f;
        acc[mf][nf][r] = val ? w3n * sp : 0.f;
      }
  }
#pragma unroll
  for (int off = 32; off > 0; off >>= 1) epart += __shfl_down(epart, off, 64);
  if (lane == 0) atomicAdd(&blockE, epart);

  __syncthreads();  // all reads of h1 done
#pragma unroll
  for (int mf = 0; mf < 2; ++mf)
#pragma unroll
    for (int nf = 0; nf < 8; ++nf)
#pragma unroll
      for (int r = 0; r < 4; ++r)
        bufA[swz(mf * 16 + q * 4 + r, n0 + nf * 16 + lm)] = f2bf(acc[mf][nf][r]);
  __syncthreads();
  if (tid == 0) atomicAdd(out, blockE + (float)vcnt * b3p[0]);

  // ---- phase 3: backward GEMM dH1 = dz2 @ W2^T ----
#pragma unroll
  for (int mf = 0; mf < 2; ++mf)
#pragma unroll
    for (int nf = 0; nf < 8; ++nf) acc[mf][nf] = (f32x4){0.f, 0.f, 0.f, 0.f};

#pragma unroll 4
  for (int kk = 0; kk < 16; ++kk) {
    short8 a[2];
#pragma unroll
    for (int mf = 0; mf < 2; ++mf)
      a[mf] = *(const short8*)&bufA[swz(mf * 16 + lm, kk * 32 + q * 8)];
#pragma unroll
    for (int nf = 0; nf < 8; ++nf) {
      short8 bfr = *(const short8*)(Wb + ((((w * 8 + nf) * 16 + kk) * 64 + lane) << 3));
#pragma unroll
      for (int mf = 0; mf < 2; ++mf)
        acc[mf][nf] = __builtin_amdgcn_mfma_f32_16x16x32_bf16(a[mf], bfr, acc[mf][nf], 0, 0, 0);
    }
  }

  // ---- phase 4: dz1 = dH1 * silu'(z1); z1 via bf16 re-MFMA ----
#pragma unroll
  for (int nf = 0; nf < 8; ++nf) {
    short8 Bh = *(const short8*)(W1hi + (((w * 8 + nf) * 64 + lane) << 3));
    float b1n = b1[n0 + nf * 16 + lm];
    f32x4 zacc[2];
#pragma unroll
    for (int mf = 0; mf < 2; ++mf) zacc[mf] = (f32x4){0.f, 0.f, 0.f, 0.f};
#pragma unroll
    for (int mf = 0; mf < 2; ++mf)
      zacc[mf] = __builtin_amdgcn_mfma_f32_16x16x32_bf16(Ah[mf], Bh, zacc[mf], 0, 0, 0);
#pragma unroll
    for (int mf = 0; mf < 2; ++mf)
#pragma unroll
      for (int r = 0; r < 4; ++r) {
        float z = zacc[mf][r] + b1n;
        float s = fsig(z);
        float sp = s * (1.f + z * (1.f - s));
        acc[mf][nf][r] *= sp;
      }
  }
  __syncthreads();  // all reads of dz2 done
#pragma unroll
  for (int mf = 0; mf < 2; ++mf)
#pragma unroll
    for (int nf = 0; nf < 8; ++nf)
#pragma unroll
      for (int r = 0; r < 4; ++r)
        bufA[swz(mf * 16 + q * 4 + r, n0 + nf * 16 + lm)] = f2bf(acc[mf][nf][r]);
  __syncthreads();

  // ---- phase 5: dh0 = dz1 @ W1^T via MFMA, K split across 4 waves ----
  {
    f32x4 pacc[2];
#pragma unroll
    for (int mf = 0; mf < 2; ++mf) pacc[mf] = (f32x4){0.f, 0.f, 0.f, 0.f};
#pragma unroll
    for (int t = 0; t < 4; ++t) {
      int kk = w * 4 + t;
      short8 b = *(const short8*)(W1p5 + ((kk * 64 + lane) << 3));
      short8 a[2];
#pragma unroll
      for (int mf = 0; mf < 2; ++mf)
        a[mf] = *(const short8*)&bufA[swz(mf * 16 + lm, kk * 32 + q * 8)];
#pragma unroll
      for (int mf = 0; mf < 2; ++mf)
        pacc[mf] = __builtin_amdgcn_mfma_f32_16x16x32_bf16(a[mf], b, pacc[mf], 0, 0, 0);
    }
    if (lm < GD) {
#pragma unroll
      for (int mf = 0; mf < 2; ++mf)
#pragma unroll
        for (int r = 0; r < 4; ++r)
          atomicAdd(&dh0s[mf * 16 + q * 4 + r][lm], pacc[mf][r]);
    }
  }
  __syncthreads();

  // ---- scatter grads ----
  {
    int e = tid >> 3, k7 = tid & 7;    // 256 threads cover 32 edges x 8
    if (e < vcnt && k7 < GD) {
      int obj = k7 >> 1, d = k7 & 1;
      atomicAdd(&out[1 + idxs[e * ARITY + obj] * 2 + d], dh0s[e][k7]);
    }
  }
}

extern "C" void kernel_launch(void* const* d_in, const int* in_sizes, int n_in,
                              void* d_out, int out_size, void* d_ws, size_t ws_size,
                              hipStream_t stream) {
  const float* x    = (const float*)d_in[0];
  const float* sig  = (const float*)d_in[1];
  const int*   ep   = (const int*)d_in[2];
  const int*   et   = (const int*)d_in[3];
  const float* pW1  = (const float*)d_in[4];
  const float* pb1  = (const float*)d_in[5];
  const float* pW2  = (const float*)d_in[6];
  const float* pb2  = (const float*)d_in[7];
  const float* pW3  = (const float*)d_in[8];
  const float* pb3  = (const float*)d_in[9];
  const float* tW1  = (const float*)d_in[10];
  const float* tb1  = (const float*)d_in[11];
  const float* tW2  = (const float*)d_in[12];
  const float* tb2  = (const float*)d_in[13];
  const float* tW3  = (const float*)d_in[14];
  const float* tb3  = (const float*)d_in[15];
  const int E2 = in_sizes[2] / 2;
  const int E3 = in_sizes[3] / 3;
  float* out = (float*)d_out;

  unsigned short* pWf = (unsigned short*)d_ws;
  unsigned short* pWb = pWf + HDIM * HDIM;
  unsigned short* tWf = pWb + HDIM * HDIM;
  unsigned short* tWb = tWf + HDIM * HDIM;
  unsigned short* pW1hi = tWb + HDIM * HDIM;
  unsigned short* pW1lo = pW1hi + 32 * 64 * 8;
  unsigned short* pW1p5 = pW1lo + 32 * 64 * 8;
  unsigned short* tW1hi = pW1p5 + 16 * 64 * 8;
  unsigned short* tW1lo = tW1hi + 32 * 64 * 8;
  unsigned short* tW1p5 = tW1lo + 32 * 64 * 8;

  hipMemsetAsync(d_out, 0, (size_t)out_size * sizeof(float), stream);
  prep_weights<<<(HDIM * HDIM + 255) / 256, 256, 0, stream>>>(pW2, tW2, pWf, pWb, tWf, tWb);
  prep_w1<<<(32 * 64 * 8 + 16 * 64 * 8 + 255) / 256, 256, 0, stream>>>(pW1, 6, 4, pW1hi, pW1lo, pW1p5);
  prep_w1<<<(32 * 64 * 8 + 16 * 64 * 8 + 255) / 256, 256, 0, stream>>>(tW1, 9, 6, tW1hi, tW1lo, tW1p5);
  energy_kernel<2><<<(E2 + TILE - 1) / TILE, TPB, 0, stream>>>(
      x, sig, ep, E2, pW1hi, pW1lo, pW1p5, pb1, pWf, pWb, pb2, pW3, pb3, out);
  energy_kernel<3><<<(E3 + TILE - 1) / TILE, TPB, 0, stream>>>(
      x, sig, et, E3, tW1hi, tW1lo, tW1p5, tb1, tWf, tWb, tb2, tW3, tb3, out);
}

// Round 7
// 857.936 us; speedup vs baseline: 1.5216x; 1.5216x over previous
//
#include <hip/hip_runtime.h>
#include <hip/hip_bf16.h>

#define HDIM 512
#define TILE 32
#define TPB 256

typedef __attribute__((ext_vector_type(8))) short short8;
typedef __attribute__((ext_vector_type(4))) short s16x4;
typedef __attribute__((ext_vector_type(4))) float f32x4;

__device__ __forceinline__ unsigned short f2bf(float x) {
  __hip_bfloat16 h = __float2bfloat16(x);
  return *reinterpret_cast<unsigned short*>(&h);
}
__device__ __forceinline__ float bf2f(unsigned short h) {
  return __uint_as_float(((unsigned)h) << 16);
}
// sigmoid via v_rcp_f32 (1-ulp) instead of IEEE divide.
__device__ __forceinline__ float fsig(float z) {
  return __builtin_amdgcn_rcpf(1.f + __expf(-z));
}
// bufA is [e][n] (TILE x 512 bf16). XOR bits 4-6 of n with e&7: b64 C-stores
// (4 consecutive n per lane) land 2-way (free); b128 B-frag reads <=4-way.
// Bijective within the row; preserves 4- and 8-element alignment.
__device__ __forceinline__ int bidx(int e, int n) {
  return e * HDIM + (n ^ ((e & 7) << 4));
}

// W2 (512x512 f32 [k][n]) -> bf16 MFMA-fragment-major. In the transposed-GEMM
// scheme these are A-fragments: lane l elem j = W[kb*32+(l>>4)*8+j][nb*16+(l&15)].
__global__ void prep_weights(const float* __restrict__ pW2, const float* __restrict__ tW2,
                             unsigned short* __restrict__ pWf, unsigned short* __restrict__ pWb,
                             unsigned short* __restrict__ tWf, unsigned short* __restrict__ tWb) {
  int i = blockIdx.x * blockDim.x + threadIdx.x;
  if (i >= HDIM * HDIM) return;
  int j  = i & 7;
  int l  = (i >> 3) & 63;
  int kb = (i >> 9) & 15;
  int nb = i >> 13;
  int kpos = kb * 32 + ((l >> 4) << 3) + j;
  int npos = nb * 16 + (l & 15);
  pWf[i] = f2bf(pW2[kpos * HDIM + npos]);
  pWb[i] = f2bf(pW2[npos * HDIM + kpos]);
  tWf[i] = f2bf(tW2[kpos * HDIM + npos]);
  tWb[i] = f2bf(tW2[npos * HDIM + kpos]);
}

// W1 ([IN][512] f32) -> layer-1 A-fragments (hi/lo split-bf16, K=32 zero-padded)
// and phase-5 A-fragments (A[g][n] = W1[g][n], g < GD).
__global__ void prep_w1(const float* __restrict__ W1, int IN, int GD,
                        unsigned short* __restrict__ hi, unsigned short* __restrict__ lo,
                        unsigned short* __restrict__ p5) {
  int i = blockIdx.x * blockDim.x + threadIdx.x;
  if (i < 32 * 64 * 8) {               // layer-1 frags: [nb=32][lane][j]
    int j = i & 7, l = (i >> 3) & 63, nb = i >> 9;
    int k = ((l >> 4) << 3) + j;
    int col = nb * 16 + (l & 15);
    float v = (k < IN) ? W1[k * HDIM + col] : 0.f;
    unsigned short h = f2bf(v);
    hi[i] = h;
    lo[i] = f2bf(v - bf2f(h));
  } else if (i < 32 * 64 * 8 + 16 * 64 * 8) {  // phase-5 frags: [kk=16][lane][j]
    int i2 = i - 32 * 64 * 8;
    int j = i2 & 7, l = (i2 >> 3) & 63, kk = i2 >> 9;
    int lm = l & 15, q = l >> 4;
    int k = kk * 32 + q * 8 + j;
    p5[i2] = f2bf((lm < GD) ? W1[lm * HDIM + k] : 0.f);
  }
}

template <int ARITY>
__global__ void __launch_bounds__(TPB)
energy_kernel(const float* __restrict__ x, const float* __restrict__ sigp,
              const int* __restrict__ edges, int Etot,
              const unsigned short* __restrict__ W1hi, const unsigned short* __restrict__ W1lo,
              const unsigned short* __restrict__ W1p5, const float* __restrict__ b1,
              const unsigned short* __restrict__ Wf, const unsigned short* __restrict__ Wb,
              const float* __restrict__ b2, const float* __restrict__ w3,
              const float* __restrict__ b3p, float* __restrict__ out) {
  constexpr int GD = 2 * ARITY;   // grad components per edge
  __shared__ __align__(16) unsigned short bufA[TILE * HDIM];  // h1 -> dz2 -> dz1 (32 KB)
  __shared__ __align__(16) float h0s[TILE][16];
  __shared__ float dh0sT[8][TILE];
  __shared__ int   idxs[TILE * ARITY];
  __shared__ float blockE;

  const int tid  = threadIdx.x;
  const int lane = tid & 63;
  const int w    = tid >> 6;            // 4 waves; wave owns n-cols [w*128, w*128+128)
  const int q    = lane >> 4;
  const int lm   = lane & 15;
  const int tile0 = blockIdx.x * TILE;
  const int vcnt  = min(TILE, Etot - tile0);
  const float sigma = sigp[0];

  // ---- phase 0: init ----
  if (tid == 0) blockE = 0.f;
  ((float*)dh0sT)[tid] = 0.f;           // 8*32 == 256 == TPB
  if (tid < TILE * ARITY) {
    int e = tid / ARITY;
    idxs[tid] = (e < vcnt) ? edges[(size_t)tile0 * ARITY + tid] : 0;
  }
  __syncthreads();
  if (tid < TILE) {
#pragma unroll
    for (int k = 0; k < 16; ++k) h0s[tid][k] = 0.f;
    if (tid < vcnt) {
#pragma unroll
      for (int o = 0; o < ARITY; ++o) {
        int id = idxs[tid * ARITY + o];
        h0s[tid][o * 2 + 0] = x[id * 2 + 0];
        h0s[tid][o * 2 + 1] = x[id * 2 + 1];
        h0s[tid][ARITY * 2 + o] = sigma;
      }
    }
  }
  __syncthreads();

  const int n0 = w * 128;

  // ---- h0 B-fragments (hi/lo split), lane gives h0[ef*16+lm][q*8+j] ----
  short8 Hh[2], Hl[2];
#pragma unroll
  for (int ef = 0; ef < 2; ++ef) {
    f32x4 v0 = {0.f, 0.f, 0.f, 0.f}, v1 = {0.f, 0.f, 0.f, 0.f};
    if (q < 2) {
      const float* p = &h0s[ef * 16 + lm][q * 8];
      v0 = *(const f32x4*)p;
      v1 = *(const f32x4*)(p + 4);
    }
#pragma unroll
    for (int j = 0; j < 4; ++j) {
      unsigned short ha = f2bf(v0[j]);
      Hh[ef][j] = (short)ha;
      Hl[ef][j] = (short)f2bf(v0[j] - bf2f(ha));
      unsigned short hb = f2bf(v1[j]);
      Hh[ef][j + 4] = (short)hb;
      Hl[ef][j + 4] = (short)f2bf(v1[j] - bf2f(hb));
    }
  }

  f32x4 acc[8][2];
#pragma unroll
  for (int mf = 0; mf < 8; ++mf)
#pragma unroll
    for (int ef = 0; ef < 2; ++ef) acc[mf][ef] = (f32x4){0.f, 0.f, 0.f, 0.f};

  // ---- phase 1: z1^T = W1^T h0^T via split-bf16 MFMA (A = W1 frags) ----
#pragma unroll
  for (int mf = 0; mf < 8; ++mf) {
    short8 A1h = *(const short8*)(W1hi + (((w * 8 + mf) * 64 + lane) << 3));
    short8 A1l = *(const short8*)(W1lo + (((w * 8 + mf) * 64 + lane) << 3));
#pragma unroll
    for (int ef = 0; ef < 2; ++ef) {
      acc[mf][ef] = __builtin_amdgcn_mfma_f32_16x16x32_bf16(A1h, Hh[ef], acc[mf][ef], 0, 0, 0);
      acc[mf][ef] = __builtin_amdgcn_mfma_f32_16x16x32_bf16(A1l, Hh[ef], acc[mf][ef], 0, 0, 0);
      acc[mf][ef] = __builtin_amdgcn_mfma_f32_16x16x32_bf16(A1h, Hl[ef], acc[mf][ef], 0, 0, 0);
    }
  }
  // silu(z1) -> bufA[e][n], one b64 per fragment (4 consecutive n, edge lm)
#pragma unroll
  for (int mf = 0; mf < 8; ++mf) {
    f32x4 b1x = *(const f32x4*)&b1[n0 + mf * 16 + q * 4];
#pragma unroll
    for (int ef = 0; ef < 2; ++ef) {
      bool val = (ef * 16 + lm) < vcnt;
      s16x4 pk;
#pragma unroll
      for (int r = 0; r < 4; ++r) {
        float z = acc[mf][ef][r] + b1x[r];
        float s = fsig(z);
        pk[r] = (short)f2bf(val ? z * s : 0.f);
      }
      *(s16x4*)&bufA[bidx(ef * 16 + lm, n0 + mf * 16 + q * 4)] = pk;
    }
  }
  __syncthreads();

  // ---- phase 2: z2^T = W2^T h1^T (A = Wf frags, B = bufA rows) ----
#pragma unroll
  for (int mf = 0; mf < 8; ++mf)
#pragma unroll
    for (int ef = 0; ef < 2; ++ef) acc[mf][ef] = (f32x4){0.f, 0.f, 0.f, 0.f};

#pragma unroll 4
  for (int kk = 0; kk < 16; ++kk) {
    short8 hb[2];
#pragma unroll
    for (int ef = 0; ef < 2; ++ef)
      hb[ef] = *(const short8*)&bufA[bidx(ef * 16 + lm, kk * 32 + q * 8)];
#pragma unroll
    for (int mf = 0; mf < 8; ++mf) {
      short8 af = *(const short8*)(Wf + ((((w * 8 + mf) * 16 + kk) * 64 + lane) << 3));
#pragma unroll
      for (int ef = 0; ef < 2; ++ef)
        acc[mf][ef] = __builtin_amdgcn_mfma_f32_16x16x32_bf16(af, hb[ef], acc[mf][ef], 0, 0, 0);
    }
  }

  // ---- epilogue fwd: energy + dz2 = w3*silu'(z2) ----
  float epart = 0.f;
#pragma unroll
  for (int mf = 0; mf < 8; ++mf) {
    f32x4 b2x = *(const f32x4*)&b2[n0 + mf * 16 + q * 4];
    f32x4 w3x = *(const f32x4*)&w3[n0 + mf * 16 + q * 4];
#pragma unroll
    for (int ef = 0; ef < 2; ++ef) {
      bool val = (ef * 16 + lm) < vcnt;
#pragma unroll
      for (int r = 0; r < 4; ++r) {
        float z = acc[mf][ef][r] + b2x[r];
        float s = fsig(z);
        float h2 = z * s;
        float sp = s * (1.f + z * (1.f - s));
        epart += val ? h2 * w3x[r] : 0.f;
        acc[mf][ef][r] = val ? w3x[r] * sp : 0.f;
      }
    }
  }
#pragma unroll
  for (int off = 32; off > 0; off >>= 1) epart += __shfl_down(epart, off, 64);
  if (lane == 0) atomicAdd(&blockE, epart);

  __syncthreads();  // all reads of h1 done
#pragma unroll
  for (int mf = 0; mf < 8; ++mf)
#pragma unroll
    for (int ef = 0; ef < 2; ++ef) {
      s16x4 pk;
#pragma unroll
      for (int r = 0; r < 4; ++r) pk[r] = (short)f2bf(acc[mf][ef][r]);
      *(s16x4*)&bufA[bidx(ef * 16 + lm, n0 + mf * 16 + q * 4)] = pk;
    }
  __syncthreads();
  if (tid == 0) atomicAdd(out, blockE + (float)vcnt * b3p[0]);

  // ---- phase 3: dH1^T = W2 dz2^T (A = Wb frags) ----
#pragma unroll
  for (int mf = 0; mf < 8; ++mf)
#pragma unroll
    for (int ef = 0; ef < 2; ++ef) acc[mf][ef] = (f32x4){0.f, 0.f, 0.f, 0.f};

#pragma unroll 4
  for (int kk = 0; kk < 16; ++kk) {
    short8 hb[2];
#pragma unroll
    for (int ef = 0; ef < 2; ++ef)
      hb[ef] = *(const short8*)&bufA[bidx(ef * 16 + lm, kk * 32 + q * 8)];
#pragma unroll
    for (int mf = 0; mf < 8; ++mf) {
      short8 af = *(const short8*)(Wb + ((((w * 8 + mf) * 16 + kk) * 64 + lane) << 3));
#pragma unroll
      for (int ef = 0; ef < 2; ++ef)
        acc[mf][ef] = __builtin_amdgcn_mfma_f32_16x16x32_bf16(af, hb[ef], acc[mf][ef], 0, 0, 0);
    }
  }

  // ---- phase 4: dz1 = dH1 * silu'(z1); z1 via bf16 re-MFMA ----
#pragma unroll
  for (int mf = 0; mf < 8; ++mf) {
    short8 A1h = *(const short8*)(W1hi + (((w * 8 + mf) * 64 + lane) << 3));
    f32x4 zacc[2];
#pragma unroll
    for (int ef = 0; ef < 2; ++ef) zacc[ef] = (f32x4){0.f, 0.f, 0.f, 0.f};
#pragma unroll
    for (int ef = 0; ef < 2; ++ef)
      zacc[ef] = __builtin_amdgcn_mfma_f32_16x16x32_bf16(A1h, Hh[ef], zacc[ef], 0, 0, 0);
    f32x4 b1x = *(const f32x4*)&b1[n0 + mf * 16 + q * 4];
#pragma unroll
    for (int ef = 0; ef < 2; ++ef)
#pragma unroll
      for (int r = 0; r < 4; ++r) {
        float z = zacc[ef][r] + b1x[r];
        float s = fsig(z);
        float sp = s * (1.f + z * (1.f - s));
        acc[mf][ef][r] *= sp;
      }
  }
  __syncthreads();  // all reads of dz2 done
#pragma unroll
  for (int mf = 0; mf < 8; ++mf)
#pragma unroll
    for (int ef = 0; ef < 2; ++ef) {
      s16x4 pk;
#pragma unroll
      for (int r = 0; r < 4; ++r) pk[r] = (short)f2bf(acc[mf][ef][r]);
      *(s16x4*)&bufA[bidx(ef * 16 + lm, n0 + mf * 16 + q * 4)] = pk;
    }
  __syncthreads();

  // ---- phase 5: dh0^T = W1 dz1^T, K(n) split across 4 waves ----
  {
    f32x4 pacc[2];
#pragma unroll
    for (int ef = 0; ef < 2; ++ef) pacc[ef] = (f32x4){0.f, 0.f, 0.f, 0.f};
#pragma unroll
    for (int t = 0; t < 4; ++t) {
      int kk = w * 4 + t;
      short8 a5 = *(const short8*)(W1p5 + ((kk * 64 + lane) << 3));
      short8 db[2];
#pragma unroll
      for (int ef = 0; ef < 2; ++ef)
        db[ef] = *(const short8*)&bufA[bidx(ef * 16 + lm, kk * 32 + q * 8)];
#pragma unroll
      for (int ef = 0; ef < 2; ++ef)
        pacc[ef] = __builtin_amdgcn_mfma_f32_16x16x32_bf16(a5, db[ef], pacc[ef], 0, 0, 0);
    }
#pragma unroll
    for (int ef = 0; ef < 2; ++ef)
#pragma unroll
      for (int r = 0; r < 4; ++r) {
        int g = q * 4 + r;
        if (g < GD) atomicAdd(&dh0sT[g][ef * 16 + lm], pacc[ef][r]);
      }
  }
  __syncthreads();

  // ---- scatter grads ----
  {
    int e = tid & 31, g = tid >> 5;     // 256 threads = 32 edges x 8 comps
    if (e < vcnt && g < GD) {
      int obj = g >> 1, d = g & 1;
      atomicAdd(&out[1 + idxs[e * ARITY + obj] * 2 + d], dh0sT[g][e]);
    }
  }
}

extern "C" void kernel_launch(void* const* d_in, const int* in_sizes, int n_in,
                              void* d_out, int out_size, void* d_ws, size_t ws_size,
                              hipStream_t stream) {
  const float* x    = (const float*)d_in[0];
  const float* sig  = (const float*)d_in[1];
  const int*   ep   = (const int*)d_in[2];
  const int*   et   = (const int*)d_in[3];
  const float* pW1  = (const float*)d_in[4];
  const float* pb1  = (const float*)d_in[5];
  const float* pW2  = (const float*)d_in[6];
  const float* pb2  = (const float*)d_in[7];
  const float* pW3  = (const float*)d_in[8];
  const float* pb3  = (const float*)d_in[9];
  const float* tW1  = (const float*)d_in[10];
  const float* tb1  = (const float*)d_in[11];
  const float* tW2  = (const float*)d_in[12];
  const float* tb2  = (const float*)d_in[13];
  const float* tW3  = (const float*)d_in[14];
  const float* tb3  = (const float*)d_in[15];
  const int E2 = in_sizes[2] / 2;
  const int E3 = in_sizes[3] / 3;
  float* out = (float*)d_out;

  unsigned short* pWf = (unsigned short*)d_ws;
  unsigned short* pWb = pWf + HDIM * HDIM;
  unsigned short* tWf = pWb + HDIM * HDIM;
  unsigned short* tWb = tWf + HDIM * HDIM;
  unsigned short* pW1hi = tWb + HDIM * HDIM;
  unsigned short* pW1lo = pW1hi + 32 * 64 * 8;
  unsigned short* pW1p5 = pW1lo + 32 * 64 * 8;
  unsigned short* tW1hi = pW1p5 + 16 * 64 * 8;
  unsigned short* tW1lo = tW1hi + 32 * 64 * 8;
  unsigned short* tW1p5 = tW1lo + 32 * 64 * 8;

  hipMemsetAsync(d_out, 0, (size_t)out_size * sizeof(float), stream);
  prep_weights<<<(HDIM * HDIM + 255) / 256, 256, 0, stream>>>(pW2, tW2, pWf, pWb, tWf, tWb);
  prep_w1<<<(32 * 64 * 8 + 16 * 64 * 8 + 255) / 256, 256, 0, stream>>>(pW1, 6, 4, pW1hi, pW1lo, pW1p5);
  prep_w1<<<(32 * 64 * 8 + 16 * 64 * 8 + 255) / 256, 256, 0, stream>>>(tW1, 9, 6, tW1hi, tW1lo, tW1p5);
  energy_kernel<2><<<(E2 + TILE - 1) / TILE, TPB, 0, stream>>>(
      x, sig, ep, E2, pW1hi, pW1lo, pW1p5, pb1, pWf, pWb, pb2, pW3, pb3, out);
  energy_kernel<3><<<(E3 + TILE - 1) / TILE, TPB, 0, stream>>>(
      x, sig, et, E3, tW1hi, tW1lo, tW1p5, tb1, tWf, tWb, tb2, tW3, tb3, out);
}

// Round 8
// 625.385 us; speedup vs baseline: 2.0874x; 1.3719x over previous
//
#include <hip/hip_runtime.h>
#include <hip/hip_bf16.h>

#define HDIM 512
#define TILE 32
#define TPB 256

typedef __attribute__((ext_vector_type(8))) short short8;
typedef __attribute__((ext_vector_type(4))) short s16x4;
typedef __attribute__((ext_vector_type(4))) float f32x4;

__device__ __forceinline__ unsigned short f2bf(float x) {
  __hip_bfloat16 h = __float2bfloat16(x);
  return *reinterpret_cast<unsigned short*>(&h);
}
__device__ __forceinline__ float bf2f(unsigned short h) {
  return __uint_as_float(((unsigned)h) << 16);
}
// sigmoid via v_rcp_f32 (1-ulp) instead of IEEE divide.
__device__ __forceinline__ float fsig(float z) {
  return __builtin_amdgcn_rcpf(1.f + __expf(-z));
}
// bufA is [e][n] (TILE x 512 bf16). XOR bits 4-6 of n with e&7: b64 C-stores
// land 2-way (free); b128 B-frag reads conflict-free (8 slots/bank = min).
__device__ __forceinline__ int bidx(int e, int n) {
  return e * HDIM + (n ^ ((e & 7) << 4));
}

// W2 (512x512 f32 [k][n]) -> bf16 MFMA-fragment-major. In the transposed-GEMM
// scheme these are A-fragments: lane l elem j = W[kb*32+(l>>4)*8+j][nb*16+(l&15)].
__global__ void prep_weights(const float* __restrict__ pW2, const float* __restrict__ tW2,
                             unsigned short* __restrict__ pWf, unsigned short* __restrict__ pWb,
                             unsigned short* __restrict__ tWf, unsigned short* __restrict__ tWb) {
  int i = blockIdx.x * blockDim.x + threadIdx.x;
  if (i >= HDIM * HDIM) return;
  int j  = i & 7;
  int l  = (i >> 3) & 63;
  int kb = (i >> 9) & 15;
  int nb = i >> 13;
  int kpos = kb * 32 + ((l >> 4) << 3) + j;
  int npos = nb * 16 + (l & 15);
  pWf[i] = f2bf(pW2[kpos * HDIM + npos]);
  pWb[i] = f2bf(pW2[npos * HDIM + kpos]);
  tWf[i] = f2bf(tW2[kpos * HDIM + npos]);
  tWb[i] = f2bf(tW2[npos * HDIM + kpos]);
}

// W1 ([IN][512] f32) -> layer-1 A-fragments (hi/lo split-bf16, K=32 zero-padded)
// and phase-5 A-fragments (A[g][n] = W1[g][n], g < GD).
__global__ void prep_w1(const float* __restrict__ W1, int IN, int GD,
                        unsigned short* __restrict__ hi, unsigned short* __restrict__ lo,
                        unsigned short* __restrict__ p5) {
  int i = blockIdx.x * blockDim.x + threadIdx.x;
  if (i < 32 * 64 * 8) {               // layer-1 frags: [nb=32][lane][j]
    int j = i & 7, l = (i >> 3) & 63, nb = i >> 9;
    int k = ((l >> 4) << 3) + j;
    int col = nb * 16 + (l & 15);
    float v = (k < IN) ? W1[k * HDIM + col] : 0.f;
    unsigned short h = f2bf(v);
    hi[i] = h;
    lo[i] = f2bf(v - bf2f(h));
  } else if (i < 32 * 64 * 8 + 16 * 64 * 8) {  // phase-5 frags: [kk=16][lane][j]
    int i2 = i - 32 * 64 * 8;
    int j = i2 & 7, l = (i2 >> 3) & 63, kk = i2 >> 9;
    int lm = l & 15, q = l >> 4;
    int k = kk * 32 + q * 8 + j;
    p5[i2] = f2bf((lm < GD) ? W1[lm * HDIM + k] : 0.f);
  }
}

template <int ARITY>
__global__ void __launch_bounds__(TPB, 2)   // clamp VGPR to 128 (empirical: 256/w) -> 4 waves/SIMD
energy_kernel(const float* __restrict__ x, const float* __restrict__ sigp,
              const int* __restrict__ edges, int Etot,
              const unsigned short* __restrict__ W1hi, const unsigned short* __restrict__ W1lo,
              const unsigned short* __restrict__ W1p5, const float* __restrict__ b1,
              const unsigned short* __restrict__ Wf, const unsigned short* __restrict__ Wb,
              const float* __restrict__ b2, const float* __restrict__ w3,
              const float* __restrict__ b3p, float* __restrict__ out) {
  constexpr int GD = 2 * ARITY;   // grad components per edge
  __shared__ __align__(16) unsigned short bufA[TILE * HDIM];  // h1 -> dz2 -> dz1 (32 KB)
  __shared__ __align__(16) float h0s[TILE][16];
  __shared__ float dh0sT[8][TILE];
  __shared__ int   idxs[TILE * ARITY];
  __shared__ float blockE;

  const int tid  = threadIdx.x;
  const int lane = tid & 63;
  const int w    = tid >> 6;            // 4 waves; wave owns n-cols [w*128, w*128+128)
  const int q    = lane >> 4;
  const int lm   = lane & 15;
  const int tile0 = blockIdx.x * TILE;
  const int vcnt  = min(TILE, Etot - tile0);
  const float sigma = sigp[0];

  // ---- phase 0: init ----
  if (tid == 0) blockE = 0.f;
  ((float*)dh0sT)[tid] = 0.f;           // 8*32 == 256 == TPB
  if (tid < TILE * ARITY) {
    int e = tid / ARITY;
    idxs[tid] = (e < vcnt) ? edges[(size_t)tile0 * ARITY + tid] : 0;
  }
  __syncthreads();
  if (tid < TILE) {
#pragma unroll
    for (int k = 0; k < 16; ++k) h0s[tid][k] = 0.f;
    if (tid < vcnt) {
#pragma unroll
      for (int o = 0; o < ARITY; ++o) {
        int id = idxs[tid * ARITY + o];
        h0s[tid][o * 2 + 0] = x[id * 2 + 0];
        h0s[tid][o * 2 + 1] = x[id * 2 + 1];
        h0s[tid][ARITY * 2 + o] = sigma;
      }
    }
  }
  __syncthreads();

  const int n0 = w * 128;

  // ---- h0 B-fragments (hi/lo split), lane gives h0[ef*16+lm][q*8+j] ----
  short8 Hh[2], Hl[2];
#pragma unroll
  for (int ef = 0; ef < 2; ++ef) {
    f32x4 v0 = {0.f, 0.f, 0.f, 0.f}, v1 = {0.f, 0.f, 0.f, 0.f};
    if (q < 2) {
      const float* p = &h0s[ef * 16 + lm][q * 8];
      v0 = *(const f32x4*)p;
      v1 = *(const f32x4*)(p + 4);
    }
#pragma unroll
    for (int j = 0; j < 4; ++j) {
      unsigned short ha = f2bf(v0[j]);
      Hh[ef][j] = (short)ha;
      Hl[ef][j] = (short)f2bf(v0[j] - bf2f(ha));
      unsigned short hb = f2bf(v1[j]);
      Hh[ef][j + 4] = (short)hb;
      Hl[ef][j + 4] = (short)f2bf(v1[j] - bf2f(hb));
    }
  }

  f32x4 acc[8][2];
#pragma unroll
  for (int mf = 0; mf < 8; ++mf)
#pragma unroll
    for (int ef = 0; ef < 2; ++ef) acc[mf][ef] = (f32x4){0.f, 0.f, 0.f, 0.f};

  // ---- phase 1: z1^T = W1^T h0^T via split-bf16 MFMA (A = W1 frags) ----
#pragma unroll
  for (int mf = 0; mf < 8; ++mf) {
    short8 A1h = *(const short8*)(W1hi + (((w * 8 + mf) * 64 + lane) << 3));
    short8 A1l = *(const short8*)(W1lo + (((w * 8 + mf) * 64 + lane) << 3));
#pragma unroll
    for (int ef = 0; ef < 2; ++ef) {
      acc[mf][ef] = __builtin_amdgcn_mfma_f32_16x16x32_bf16(A1h, Hh[ef], acc[mf][ef], 0, 0, 0);
      acc[mf][ef] = __builtin_amdgcn_mfma_f32_16x16x32_bf16(A1l, Hh[ef], acc[mf][ef], 0, 0, 0);
      acc[mf][ef] = __builtin_amdgcn_mfma_f32_16x16x32_bf16(A1h, Hl[ef], acc[mf][ef], 0, 0, 0);
    }
  }
  // silu(z1) -> bufA[e][n], one b64 per fragment (4 consecutive n, edge lm)
#pragma unroll
  for (int mf = 0; mf < 8; ++mf) {
    f32x4 b1x = *(const f32x4*)&b1[n0 + mf * 16 + q * 4];
#pragma unroll
    for (int ef = 0; ef < 2; ++ef) {
      bool val = (ef * 16 + lm) < vcnt;
      s16x4 pk;
#pragma unroll
      for (int r = 0; r < 4; ++r) {
        float z = acc[mf][ef][r] + b1x[r];
        float s = fsig(z);
        pk[r] = (short)f2bf(val ? z * s : 0.f);
      }
      *(s16x4*)&bufA[bidx(ef * 16 + lm, n0 + mf * 16 + q * 4)] = pk;
    }
  }
  __syncthreads();

  // ---- phase 2: z2^T = W2^T h1^T (A = Wf frags, B = bufA rows) ----
#pragma unroll
  for (int mf = 0; mf < 8; ++mf)
#pragma unroll
    for (int ef = 0; ef < 2; ++ef) acc[mf][ef] = (f32x4){0.f, 0.f, 0.f, 0.f};

#pragma unroll 4
  for (int kk = 0; kk < 16; ++kk) {
    short8 hb[2];
#pragma unroll
    for (int ef = 0; ef < 2; ++ef)
      hb[ef] = *(const short8*)&bufA[bidx(ef * 16 + lm, kk * 32 + q * 8)];
#pragma unroll
    for (int mf = 0; mf < 8; ++mf) {
      short8 af = *(const short8*)(Wf + ((((w * 8 + mf) * 16 + kk) * 64 + lane) << 3));
#pragma unroll
      for (int ef = 0; ef < 2; ++ef)
        acc[mf][ef] = __builtin_amdgcn_mfma_f32_16x16x32_bf16(af, hb[ef], acc[mf][ef], 0, 0, 0);
    }
  }

  // ---- epilogue fwd: energy + dz2 = w3*silu'(z2) ----
  float epart = 0.f;
#pragma unroll
  for (int mf = 0; mf < 8; ++mf) {
    f32x4 b2x = *(const f32x4*)&b2[n0 + mf * 16 + q * 4];
    f32x4 w3x = *(const f32x4*)&w3[n0 + mf * 16 + q * 4];
#pragma unroll
    for (int ef = 0; ef < 2; ++ef) {
      bool val = (ef * 16 + lm) < vcnt;
#pragma unroll
      for (int r = 0; r < 4; ++r) {
        float z = acc[mf][ef][r] + b2x[r];
        float s = fsig(z);
        float h2 = z * s;
        float sp = s * (1.f + z * (1.f - s));
        epart += val ? h2 * w3x[r] : 0.f;
        acc[mf][ef][r] = val ? w3x[r] * sp : 0.f;
      }
    }
  }
#pragma unroll
  for (int off = 32; off > 0; off >>= 1) epart += __shfl_down(epart, off, 64);
  if (lane == 0) atomicAdd(&blockE, epart);

  __syncthreads();  // all reads of h1 done
#pragma unroll
  for (int mf = 0; mf < 8; ++mf)
#pragma unroll
    for (int ef = 0; ef < 2; ++ef) {
      s16x4 pk;
#pragma unroll
      for (int r = 0; r < 4; ++r) pk[r] = (short)f2bf(acc[mf][ef][r]);
      *(s16x4*)&bufA[bidx(ef * 16 + lm, n0 + mf * 16 + q * 4)] = pk;
    }
  __syncthreads();
  if (tid == 0) atomicAdd(out, blockE + (float)vcnt * b3p[0]);

  // ---- phase 3: dH1^T = W2 dz2^T (A = Wb frags) ----
#pragma unroll
  for (int mf = 0; mf < 8; ++mf)
#pragma unroll
    for (int ef = 0; ef < 2; ++ef) acc[mf][ef] = (f32x4){0.f, 0.f, 0.f, 0.f};

#pragma unroll 4
  for (int kk = 0; kk < 16; ++kk) {
    short8 hb[2];
#pragma unroll
    for (int ef = 0; ef < 2; ++ef)
      hb[ef] = *(const short8*)&bufA[bidx(ef * 16 + lm, kk * 32 + q * 8)];
#pragma unroll
    for (int mf = 0; mf < 8; ++mf) {
      short8 af = *(const short8*)(Wb + ((((w * 8 + mf) * 16 + kk) * 64 + lane) << 3));
#pragma unroll
      for (int ef = 0; ef < 2; ++ef)
        acc[mf][ef] = __builtin_amdgcn_mfma_f32_16x16x32_bf16(af, hb[ef], acc[mf][ef], 0, 0, 0);
    }
  }

  // ---- phase 4: dz1 = dH1 * silu'(z1); z1 via bf16 re-MFMA ----
#pragma unroll
  for (int mf = 0; mf < 8; ++mf) {
    short8 A1h = *(const short8*)(W1hi + (((w * 8 + mf) * 64 + lane) << 3));
    f32x4 zacc[2];
#pragma unroll
    for (int ef = 0; ef < 2; ++ef) zacc[ef] = (f32x4){0.f, 0.f, 0.f, 0.f};
#pragma unroll
    for (int ef = 0; ef < 2; ++ef)
      zacc[ef] = __builtin_amdgcn_mfma_f32_16x16x32_bf16(A1h, Hh[ef], zacc[ef], 0, 0, 0);
    f32x4 b1x = *(const f32x4*)&b1[n0 + mf * 16 + q * 4];
#pragma unroll
    for (int ef = 0; ef < 2; ++ef)
#pragma unroll
      for (int r = 0; r < 4; ++r) {
        float z = zacc[ef][r] + b1x[r];
        float s = fsig(z);
        float sp = s * (1.f + z * (1.f - s));
        acc[mf][ef][r] *= sp;
      }
  }
  __syncthreads();  // all reads of dz2 done
#pragma unroll
  for (int mf = 0; mf < 8; ++mf)
#pragma unroll
    for (int ef = 0; ef < 2; ++ef) {
      s16x4 pk;
#pragma unroll
      for (int r = 0; r < 4; ++r) pk[r] = (short)f2bf(acc[mf][ef][r]);
      *(s16x4*)&bufA[bidx(ef * 16 + lm, n0 + mf * 16 + q * 4)] = pk;
    }
  __syncthreads();

  // ---- phase 5: dh0^T = W1 dz1^T, K(n) split across 4 waves ----
  {
    f32x4 pacc[2];
#pragma unroll
    for (int ef = 0; ef < 2; ++ef) pacc[ef] = (f32x4){0.f, 0.f, 0.f, 0.f};
#pragma unroll
    for (int t = 0; t < 4; ++t) {
      int kk = w * 4 + t;
      short8 a5 = *(const short8*)(W1p5 + ((kk * 64 + lane) << 3));
      short8 db[2];
#pragma unroll
      for (int ef = 0; ef < 2; ++ef)
        db[ef] = *(const short8*)&bufA[bidx(ef * 16 + lm, kk * 32 + q * 8)];
#pragma unroll
      for (int ef = 0; ef < 2; ++ef)
        pacc[ef] = __builtin_amdgcn_mfma_f32_16x16x32_bf16(a5, db[ef], pacc[ef], 0, 0, 0);
    }
#pragma unroll
    for (int ef = 0; ef < 2; ++ef)
#pragma unroll
      for (int r = 0; r < 4; ++r) {
        int g = q * 4 + r;
        if (g < GD) atomicAdd(&dh0sT[g][ef * 16 + lm], pacc[ef][r]);
      }
  }
  __syncthreads();

  // ---- scatter grads ----
  {
    int e = tid & 31, g = tid >> 5;     // 256 threads = 32 edges x 8 comps
    if (e < vcnt && g < GD) {
      int obj = g >> 1, d = g & 1;
      atomicAdd(&out[1 + idxs[e * ARITY + obj] * 2 + d], dh0sT[g][e]);
    }
  }
}

extern "C" void kernel_launch(void* const* d_in, const int* in_sizes, int n_in,
                              void* d_out, int out_size, void* d_ws, size_t ws_size,
                              hipStream_t stream) {
  const float* x    = (const float*)d_in[0];
  const float* sig  = (const float*)d_in[1];
  const int*   ep   = (const int*)d_in[2];
  const int*   et   = (const int*)d_in[3];
  const float* pW1  = (const float*)d_in[4];
  const float* pb1  = (const float*)d_in[5];
  const float* pW2  = (const float*)d_in[6];
  const float* pb2  = (const float*)d_in[7];
  const float* pW3  = (const float*)d_in[8];
  const float* pb3  = (const float*)d_in[9];
  const float* tW1  = (const float*)d_in[10];
  const float* tb1  = (const float*)d_in[11];
  const float* tW2  = (const float*)d_in[12];
  const float* tb2  = (const float*)d_in[13];
  const float* tW3  = (const float*)d_in[14];
  const float* tb3  = (const float*)d_in[15];
  const int E2 = in_sizes[2] / 2;
  const int E3 = in_sizes[3] / 3;
  float* out = (float*)d_out;

  unsigned short* pWf = (unsigned short*)d_ws;
  unsigned short* pWb = pWf + HDIM * HDIM;
  unsigned short* tWf = pWb + HDIM * HDIM;
  unsigned short* tWb = tWf + HDIM * HDIM;
  unsigned short* pW1hi = tWb + HDIM * HDIM;
  unsigned short* pW1lo = pW1hi + 32 * 64 * 8;
  unsigned short* pW1p5 = pW1lo + 32 * 64 * 8;
  unsigned short* tW1hi = pW1p5 + 16 * 64 * 8;
  unsigned short* tW1lo = tW1hi + 32 * 64 * 8;
  unsigned short* tW1p5 = tW1lo + 32 * 64 * 8;

  hipMemsetAsync(d_out, 0, (size_t)out_size * sizeof(float), stream);
  prep_weights<<<(HDIM * HDIM + 255) / 256, 256, 0, stream>>>(pW2, tW2, pWf, pWb, tWf, tWb);
  prep_w1<<<(32 * 64 * 8 + 16 * 64 * 8 + 255) / 256, 256, 0, stream>>>(pW1, 6, 4, pW1hi, pW1lo, pW1p5);
  prep_w1<<<(32 * 64 * 8 + 16 * 64 * 8 + 255) / 256, 256, 0, stream>>>(tW1, 9, 6, tW1hi, tW1lo, tW1p5);
  energy_kernel<2><<<(E2 + TILE - 1) / TILE, TPB, 0, stream>>>(
      x, sig, ep, E2, pW1hi, pW1lo, pW1p5, pb1, pWf, pWb, pb2, pW3, pb3, out);
  energy_kernel<3><<<(E3 + TILE - 1) / TILE, TPB, 0, stream>>>(
      x, sig, et, E3, tW1hi, tW1lo, tW1p5, tb1, tWf, tWb, tb2, tW3, tb3, out);
}